// Round 1
// baseline (812.587 us; speedup 1.0000x reference)
//
#include <hip/hip_runtime.h>
#include <hip/hip_bf16.h>
#include <stdint.h>
#include <stddef.h>

typedef __attribute__((ext_vector_type(8))) short short8;
typedef __attribute__((ext_vector_type(4))) float f32x4;

#define NTOK 32768
#define DIN 512
#define HID 1024
#define DOUT 256
#define NEXP 10

__device__ __forceinline__ unsigned short f2bf(float f) {
  unsigned int u = __float_as_uint(f);
  u += 0x7fffu + ((u >> 16) & 1u);   // round-to-nearest-even
  return (unsigned short)(u >> 16);
}

// ---------------- Wr transpose: [512][10] f32 -> [10][512] f32 -------------
__global__ void k_transpose_wr(const float* __restrict__ wr, float* __restrict__ wrt) {
  for (int i = threadIdx.x; i < DIN * NEXP; i += 256) {
    int d = i / NEXP, e = i % NEXP;
    wrt[e * DIN + d] = wr[i];
  }
}

// ---------- generic [E][R][C] f32 -> [E][C][R] bf16 (ushort bits) ----------
__global__ __launch_bounds__(256) void k_transpose_conv(
    const float* __restrict__ in, unsigned short* __restrict__ out, int R, int C) {
  __shared__ unsigned short tile[64][72];
  int tid = threadIdx.x;
  const float* ip = in + ((size_t)blockIdx.z * R + blockIdx.y * 64) * C + blockIdx.x * 64;
  int r = tid >> 2, c0 = (tid & 3) * 16;
  const float* p = ip + (size_t)r * C + c0;
#pragma unroll
  for (int j = 0; j < 16; j += 4) {
    float4 v = *(const float4*)(p + j);
    tile[r][c0 + j + 0] = f2bf(v.x);
    tile[r][c0 + j + 1] = f2bf(v.y);
    tile[r][c0 + j + 2] = f2bf(v.z);
    tile[r][c0 + j + 3] = f2bf(v.w);
  }
  __syncthreads();
  unsigned short* op = out + ((size_t)blockIdx.z * C + blockIdx.x * 64) * R + blockIdx.y * 64;
  int c = tid >> 2, r0 = (tid & 3) * 16;
  unsigned short* q = op + (size_t)c * R + r0;
  union { short8 v; unsigned short u[8]; } t0, t1;
#pragma unroll
  for (int j = 0; j < 8; j++) { t0.u[j] = tile[r0 + j][c]; t1.u[j] = tile[r0 + 8 + j][c]; }
  *(short8*)(q) = t0.v;
  *(short8*)(q + 8) = t1.v;
}

// ----------------- router: logits, softmax, top-2, expert lists ------------
// One wave per token, 16 tokens per wave, 64 tokens per block.
// Block-level histogram -> ~10 global atomics per block (contention fix).
__global__ __launch_bounds__(256) void k_router(
    const float* __restrict__ x, const float* __restrict__ spike,
    const float* __restrict__ wrt, const float* __restrict__ br,
    unsigned short* __restrict__ xb, int* __restrict__ cnt,
    int* __restrict__ tok, float* __restrict__ wgt) {
  __shared__ int s_i0[64], s_i1[64];
  __shared__ float s_w0[64], s_w1[64];
  __shared__ int hist[NEXP], base_[NEXP], loc[NEXP];
  int tid = threadIdx.x, wave = tid >> 6, lane = tid & 63;
  if (tid < NEXP) { hist[tid] = 0; loc[tid] = 0; }
  __syncthreads();
  for (int t = 0; t < 16; t++) {
    int slot = wave * 16 + t;
    int b = blockIdx.x * 64 + slot;
    const float* xr = x + (size_t)b * DIN;
    float xv[8];
#pragma unroll
    for (int k = 0; k < 8; k++) xv[k] = xr[lane + 64 * k];   // coalesced
    unsigned short* xo = xb + (size_t)b * DIN;
#pragma unroll
    for (int k = 0; k < 8; k++) xo[lane + 64 * k] = f2bf(xv[k]);
    float lg[NEXP];
#pragma unroll
    for (int e = 0; e < NEXP; e++) {
      const float* w = wrt + e * DIN;
      float s = 0.f;
#pragma unroll
      for (int k = 0; k < 8; k++) s += xv[k] * w[lane + 64 * k];
      lg[e] = s;
    }
#pragma unroll
    for (int off = 32; off > 0; off >>= 1) {
#pragma unroll
      for (int e = 0; e < NEXP; e++) lg[e] += __shfl_xor(lg[e], off);
    }
    float sv = spike[(size_t)b * 16 + (lane & 15)];
    sv += __shfl_xor(sv, 8); sv += __shfl_xor(sv, 4);
    sv += __shfl_xor(sv, 2); sv += __shfl_xor(sv, 1);
    float avg = sv * 0.0625f;
#pragma unroll
    for (int e = 0; e < NEXP; e++) lg[e] += br[e];
    lg[8] += avg; lg[9] += avg;
    float mx = lg[0];
#pragma unroll
    for (int e = 1; e < NEXP; e++) mx = fmaxf(mx, lg[e]);
    float p[NEXP], ps = 0.f;
#pragma unroll
    for (int e = 0; e < NEXP; e++) { p[e] = __expf(lg[e] - mx); ps += p[e]; }
    int i0 = 0; float p0 = p[0];
#pragma unroll
    for (int e = 1; e < NEXP; e++) if (p[e] > p0) { p0 = p[e]; i0 = e; }
    float p1 = -1.f; int i1 = 0;
#pragma unroll
    for (int e = 0; e < NEXP; e++) if (e != i0 && p[e] > p1) { p1 = p[e]; i1 = e; }
    // norm = (p/ps) / ((p0+p1)/ps + 1e-9) = p / (p0+p1+ps*1e-9)
    float inv = 1.f / (p0 + p1 + ps * 1e-9f);
    if (lane == 0) {
      s_i0[slot] = i0; s_i1[slot] = i1;
      s_w0[slot] = p0 * inv; s_w1[slot] = p1 * inv;
      atomicAdd(&hist[i0], 1); atomicAdd(&hist[i1], 1);   // LDS atomics
    }
  }
  __syncthreads();
  if (tid < NEXP) base_[tid] = atomicAdd(&cnt[tid], hist[tid]);  // global, 10/block
  __syncthreads();
  if (tid < 64) {
    int b = blockIdx.x * 64 + tid;
    int i0 = s_i0[tid], i1 = s_i1[tid];
    int s0 = base_[i0] + atomicAdd(&loc[i0], 1);
    tok[i0 * NTOK + s0] = b; wgt[i0 * NTOK + s0] = s_w0[tid];
    int s1 = base_[i1] + atomicAdd(&loc[i1], 1);
    tok[i1 * NTOK + s1] = b; wgt[i1 * NTOK + s1] = s_w1[tid];
  }
}

// --------- fused grouped expert kernel: out += w * (relu(x W1 + b1) W2 + b2)
// grid (512 tiles, 10 experts), block 256 = 4 waves in 2x2 (wm x wn).
// Tile: 64 tokens x 256 out; hidden streamed in 4 chunks of 256.
// MFMA A/B frags loaded directly (16B/lane); h round-trips via swizzled LDS.
__global__ __launch_bounds__(256, 2) void k_moe(
    const unsigned short* __restrict__ xb, const unsigned short* __restrict__ w1t,
    const unsigned short* __restrict__ w2t, const float* __restrict__ b1,
    const float* __restrict__ b2, const int* __restrict__ cnt,
    const int* __restrict__ tok, const float* __restrict__ wgt,
    float* __restrict__ out) {
  int e = blockIdx.y;
  int n = cnt[e];
  int tile = blockIdx.x;
  if (tile * 64 >= n) return;
  __shared__ unsigned short hlds[64 * 256];   // 32 KB, XOR-swizzled
  __shared__ int stok[64];
  __shared__ float swgt[64];
  int tid = threadIdx.x;
  if (tid < 64) {
    int idx = tile * 64 + tid;
    bool v = idx < n;
    stok[tid] = v ? tok[e * NTOK + idx] : 0;
    swgt[tid] = v ? wgt[e * NTOK + idx] : 0.f;
  }
  __syncthreads();
  int wave = tid >> 6, lane = tid & 63, quad = lane >> 4, l16 = lane & 15;
  int wm = wave & 1, wn = wave >> 1;
  int tokm[2];
#pragma unroll
  for (int mt = 0; mt < 2; mt++) tokm[mt] = stok[wm * 32 + mt * 16 + l16];
  const unsigned short* w1e = w1t + (size_t)e * HID * DIN;   // [h][d]
  const unsigned short* w2e = w2t + (size_t)e * DOUT * HID;  // [o][h]
  f32x4 acc2[2][8];
#pragma unroll
  for (int nt = 0; nt < 8; nt++) {
    float bv = b2[e * DOUT + wn * 128 + nt * 16 + l16];
#pragma unroll
    for (int mt = 0; mt < 2; mt++) acc2[mt][nt] = (f32x4){bv, bv, bv, bv};
  }
  for (int hc = 0; hc < 4; hc++) {
    // ---- GEMM1: h[64 x 256] = x[64 x 512] @ W1T-chunk, + b1, relu ----
    f32x4 acc1[2][8];
#pragma unroll
    for (int nt = 0; nt < 8; nt++) {
      float bv = b1[e * HID + hc * 256 + wn * 128 + nt * 16 + l16];
#pragma unroll
      for (int mt = 0; mt < 2; mt++) acc1[mt][nt] = (f32x4){bv, bv, bv, bv};
    }
    for (int k = 0; k < 16; k++) {
      short8 a[2], bb[8];
#pragma unroll
      for (int mt = 0; mt < 2; mt++)
        a[mt] = *(const short8*)(xb + (size_t)tokm[mt] * DIN + k * 32 + quad * 8);
#pragma unroll
      for (int nt = 0; nt < 8; nt++)
        bb[nt] = *(const short8*)(w1e +
            (size_t)(hc * 256 + wn * 128 + nt * 16 + l16) * DIN + k * 32 + quad * 8);
#pragma unroll
      for (int mt = 0; mt < 2; mt++)
#pragma unroll
        for (int nt = 0; nt < 8; nt++)
          acc1[mt][nt] = __builtin_amdgcn_mfma_f32_16x16x32_bf16(a[mt], bb[nt], acc1[mt][nt], 0, 0, 0);
    }
    __syncthreads();   // previous chunk's GEMM2 reads done
    // relu + bf16 + swizzled store (C-layout -> LDS [m][k])
#pragma unroll
    for (int mt = 0; mt < 2; mt++) {
      int mbase = wm * 32 + mt * 16 + quad * 4;
#pragma unroll
      for (int nt = 0; nt < 8; nt++) {
        int col = wn * 128 + nt * 16 + l16;
        int g = col >> 3, co = col & 7;
#pragma unroll
        for (int r = 0; r < 4; r++) {
          int mm = mbase + r;
          int sw = (mm + (mm >> 3)) & 7;
          float v = acc1[mt][nt][r];
          hlds[mm * 256 + (((g ^ sw)) << 3) + co] = f2bf(v > 0.f ? v : 0.f);
        }
      }
    }
    __syncthreads();
    // ---- GEMM2: acc2 += h[64 x 256] @ W2T-chunk ----
    for (int k2 = 0; k2 < 8; k2++) {
      short8 a[2], bb[8];
#pragma unroll
      for (int mt = 0; mt < 2; mt++) {
        int mm = wm * 32 + mt * 16 + l16;
        int sw = (mm + (mm >> 3)) & 7;
        int g = (k2 << 2) + quad;
        a[mt] = *(const short8*)(&hlds[mm * 256 + ((g ^ sw) << 3)]);
      }
#pragma unroll
      for (int nt = 0; nt < 8; nt++)
        bb[nt] = *(const short8*)(w2e +
            (size_t)(wn * 128 + nt * 16 + l16) * HID + hc * 256 + k2 * 32 + quad * 8);
#pragma unroll
      for (int mt = 0; mt < 2; mt++)
#pragma unroll
        for (int nt = 0; nt < 8; nt++)
          acc2[mt][nt] = __builtin_amdgcn_mfma_f32_16x16x32_bf16(a[mt], bb[nt], acc2[mt][nt], 0, 0, 0);
    }
  }
  // ---- epilogue: gate-weighted atomic accumulate ----
#pragma unroll
  for (int mt = 0; mt < 2; mt++) {
#pragma unroll
    for (int r = 0; r < 4; r++) {
      int m = wm * 32 + mt * 16 + quad * 4 + r;
      float wv = swgt[m];
      if (wv != 0.f) {
        int t = stok[m];
        float* op = out + (size_t)t * DOUT + wn * 128 + l16;
#pragma unroll
        for (int nt = 0; nt < 8; nt++)
          atomicAdd(op + nt * 16, acc2[mt][nt][r] * wv);
      }
    }
  }
}

extern "C" void kernel_launch(void* const* d_in, const int* in_sizes, int n_in,
                              void* d_out, int out_size, void* d_ws, size_t ws_size,
                              hipStream_t stream) {
  (void)in_sizes; (void)n_in; (void)ws_size;
  const float* x     = (const float*)d_in[0];
  const float* spike = (const float*)d_in[1];
  const float* Wr    = (const float*)d_in[2];
  const float* br    = (const float*)d_in[3];
  const float* W1    = (const float*)d_in[4];
  const float* b1    = (const float*)d_in[5];
  const float* W2    = (const float*)d_in[6];
  const float* b2    = (const float*)d_in[7];
  float* out = (float*)d_out;
  char* ws = (char*)d_ws;
  // workspace layout (bytes)
  unsigned short* xb  = (unsigned short*)(ws + 0);          // 33,554,432
  unsigned short* w1t = (unsigned short*)(ws + 33554432);   // 10,485,760
  unsigned short* w2t = (unsigned short*)(ws + 44040192);   //  5,242,880
  float* wrt          = (float*)(ws + 49283072);            //     20,480
  int*   cnt          = (int*)(ws + 49303552);              //         64
  int*   tok          = (int*)(ws + 49303616);              //  1,310,720
  float* wgt          = (float*)(ws + 50614336);            //  1,310,720

  hipMemsetAsync(cnt, 0, 64, stream);
  hipMemsetAsync(out, 0, (size_t)out_size * sizeof(float), stream);
  k_transpose_wr<<<1, 256, 0, stream>>>(Wr, wrt);
  k_transpose_conv<<<dim3(16, 8, 10), 256, 0, stream>>>(W1, w1t, DIN, HID);
  k_transpose_conv<<<dim3(4, 16, 10), 256, 0, stream>>>(W2, w2t, HID, DOUT);
  k_router<<<512, 256, 0, stream>>>(x, spike, wrt, br, xb, cnt, tok, wgt);
  k_moe<<<dim3(512, NEXP), 256, 0, stream>>>(xb, w1t, w2t, b1, b2, cnt, tok, wgt, out);
}

// Round 2
// 398.882 us; speedup vs baseline: 2.0372x; 2.0372x over previous
//
#include <hip/hip_runtime.h>
#include <hip/hip_bf16.h>
#include <stdint.h>
#include <stddef.h>

typedef __attribute__((ext_vector_type(8))) short short8;
typedef __attribute__((ext_vector_type(4))) float f32x4;

#define NTOK 32768
#define DIN 512
#define HID 1024
#define DOUT 256
#define NEXP 10

__device__ __forceinline__ unsigned short f2bf(float f) {
  unsigned int u = __float_as_uint(f);
  u += 0x7fffu + ((u >> 16) & 1u);   // round-to-nearest-even
  return (unsigned short)(u >> 16);
}

// async 16B/lane global->LDS DMA (dest = wave-uniform base + lane*16)
__device__ __forceinline__ void gld16(void* lds, const void* g) {
  __builtin_amdgcn_global_load_lds(
      (const __attribute__((address_space(1))) unsigned int*)g,
      (__attribute__((address_space(3))) unsigned int*)lds, 16, 0, 0);
}

// ---------------- Wr transpose: [512][10] f32 -> [10][512] f32 -------------
__global__ void k_transpose_wr(const float* __restrict__ wr, float* __restrict__ wrt) {
  for (int i = threadIdx.x; i < DIN * NEXP; i += 256) {
    int d = i / NEXP, e = i % NEXP;
    wrt[e * DIN + d] = wr[i];
  }
}

// ---------- generic [E][R][C] f32 -> [E][C][R] bf16 (ushort bits) ----------
__global__ __launch_bounds__(256) void k_transpose_conv(
    const float* __restrict__ in, unsigned short* __restrict__ out, int R, int C) {
  __shared__ unsigned short tile[64][72];
  int tid = threadIdx.x;
  const float* ip = in + ((size_t)blockIdx.z * R + blockIdx.y * 64) * C + blockIdx.x * 64;
  int r = tid >> 2, c0 = (tid & 3) * 16;
  const float* p = ip + (size_t)r * C + c0;
#pragma unroll
  for (int j = 0; j < 16; j += 4) {
    float4 v = *(const float4*)(p + j);
    tile[r][c0 + j + 0] = f2bf(v.x);
    tile[r][c0 + j + 1] = f2bf(v.y);
    tile[r][c0 + j + 2] = f2bf(v.z);
    tile[r][c0 + j + 3] = f2bf(v.w);
  }
  __syncthreads();
  unsigned short* op = out + ((size_t)blockIdx.z * C + blockIdx.x * 64) * R + blockIdx.y * 64;
  int c = tid >> 2, r0 = (tid & 3) * 16;
  unsigned short* q = op + (size_t)c * R + r0;
  union { short8 v; unsigned short u[8]; } t0, t1;
#pragma unroll
  for (int j = 0; j < 8; j++) { t0.u[j] = tile[r0 + j][c]; t1.u[j] = tile[r0 + 8 + j][c]; }
  *(short8*)(q) = t0.v;
  *(short8*)(q + 8) = t1.v;
}

// ----------------- router: logits, softmax, top-2, expert lists ------------
__global__ __launch_bounds__(256) void k_router(
    const float* __restrict__ x, const float* __restrict__ spike,
    const float* __restrict__ wrt, const float* __restrict__ br,
    unsigned short* __restrict__ xb, int* __restrict__ cnt,
    int* __restrict__ tok, float* __restrict__ wgt) {
  __shared__ int s_i0[64], s_i1[64];
  __shared__ float s_w0[64], s_w1[64];
  __shared__ int hist[NEXP], base_[NEXP], loc[NEXP];
  int tid = threadIdx.x, wave = tid >> 6, lane = tid & 63;
  if (tid < NEXP) { hist[tid] = 0; loc[tid] = 0; }
  __syncthreads();
  for (int t = 0; t < 16; t++) {
    int slot = wave * 16 + t;
    int b = blockIdx.x * 64 + slot;
    const float* xr = x + (size_t)b * DIN;
    float xv[8];
#pragma unroll
    for (int k = 0; k < 8; k++) xv[k] = xr[lane + 64 * k];   // coalesced
    unsigned short* xo = xb + (size_t)b * DIN;
#pragma unroll
    for (int k = 0; k < 8; k++) xo[lane + 64 * k] = f2bf(xv[k]);
    float lg[NEXP];
#pragma unroll
    for (int e = 0; e < NEXP; e++) {
      const float* w = wrt + e * DIN;
      float s = 0.f;
#pragma unroll
      for (int k = 0; k < 8; k++) s += xv[k] * w[lane + 64 * k];
      lg[e] = s;
    }
#pragma unroll
    for (int off = 32; off > 0; off >>= 1) {
#pragma unroll
      for (int e = 0; e < NEXP; e++) lg[e] += __shfl_xor(lg[e], off);
    }
    float sv = spike[(size_t)b * 16 + (lane & 15)];
    sv += __shfl_xor(sv, 8); sv += __shfl_xor(sv, 4);
    sv += __shfl_xor(sv, 2); sv += __shfl_xor(sv, 1);
    float avg = sv * 0.0625f;
#pragma unroll
    for (int e = 0; e < NEXP; e++) lg[e] += br[e];
    lg[8] += avg; lg[9] += avg;
    float mx = lg[0];
#pragma unroll
    for (int e = 1; e < NEXP; e++) mx = fmaxf(mx, lg[e]);
    float p[NEXP], ps = 0.f;
#pragma unroll
    for (int e = 0; e < NEXP; e++) { p[e] = __expf(lg[e] - mx); ps += p[e]; }
    int i0 = 0; float p0 = p[0];
#pragma unroll
    for (int e = 1; e < NEXP; e++) if (p[e] > p0) { p0 = p[e]; i0 = e; }
    float p1 = -1.f; int i1 = 0;
#pragma unroll
    for (int e = 0; e < NEXP; e++) if (e != i0 && p[e] > p1) { p1 = p[e]; i1 = e; }
    float inv = 1.f / (p0 + p1 + ps * 1e-9f);
    if (lane == 0) {
      s_i0[slot] = i0; s_i1[slot] = i1;
      s_w0[slot] = p0 * inv; s_w1[slot] = p1 * inv;
      atomicAdd(&hist[i0], 1); atomicAdd(&hist[i1], 1);
    }
  }
  __syncthreads();
  if (tid < NEXP) base_[tid] = atomicAdd(&cnt[tid], hist[tid]);
  __syncthreads();
  if (tid < 64) {
    int b = blockIdx.x * 64 + tid;
    int i0 = s_i0[tid], i1 = s_i1[tid];
    int s0 = base_[i0] + atomicAdd(&loc[i0], 1);
    tok[i0 * NTOK + s0] = b; wgt[i0 * NTOK + s0] = s_w0[tid];
    int s1 = base_[i1] + atomicAdd(&loc[i1], 1);
    tok[i1 * NTOK + s1] = b; wgt[i1 * NTOK + s1] = s_w1[tid];
  }
}

// --------- fused grouped expert kernel: out += w * (relu(x W1 + b1) W2 + b2)
// m97-style: all operands via global_load_lds into XOR-swizzled LDS.
// Tile M=64 tokens x N=256 out, hidden chunk HC=128 (8 chunks), BK=64.
// 4 waves in 2x2 (wm x wn). LDS 72.5 KB -> 2 blocks/CU.
__global__ __launch_bounds__(256, 2) void k_moe(
    const unsigned short* __restrict__ xb, const unsigned short* __restrict__ w1t,
    const unsigned short* __restrict__ w2t, const float* __restrict__ b1,
    const float* __restrict__ b2, const int* __restrict__ cnt,
    const int* __restrict__ tok, const float* __restrict__ wgt,
    float* __restrict__ out) {
  int e = blockIdx.y;
  int n = cnt[e];
  int tile = blockIdx.x;
  if (tile * 64 >= n) return;
  __shared__ unsigned short xa[64 * 64];     //  8 KB  x-tile   [64 tok x 64 k]
  __shared__ unsigned short b1s[128 * 64];   // 16 KB  W1 tile  [128 h  x 64 k]
  __shared__ unsigned short b2s[256 * 64];   // 32 KB  W2 tile  [256 o  x 64 k]
  __shared__ unsigned short hs[64 * 128];    // 16 KB  h chunk  [64 tok x 128 h]
  __shared__ int stok[64];
  __shared__ float swgt[64];
  int tid = threadIdx.x;
  if (tid < 64) {
    int idx = tile * 64 + tid;
    bool v = idx < n;
    stok[tid] = v ? tok[e * NTOK + idx] : 0;
    swgt[tid] = v ? wgt[e * NTOK + idx] : 0.f;
  }
  __syncthreads();
  int wave = tid >> 6, lane = tid & 63, quad = lane >> 4, l16 = lane & 15;
  int wm = wave & 1, wn = wave >> 1;
  // ---- staging constants: thread owns 16B chunk (row srow(+32s), col c8*8)
  int srow = tid >> 3;                          // 0..31
  int c8 = (tid & 7) ^ (srow & 7);              // inverse XOR swizzle on source
  const unsigned short* gx0 = xb + (size_t)stok[srow] * DIN + c8 * 8;
  const unsigned short* gx1 = xb + (size_t)stok[32 + srow] * DIN + c8 * 8;
  const unsigned short* w1e = w1t + (size_t)e * HID * DIN;   // [h][d]
  const unsigned short* w2e = w2t + (size_t)e * DOUT * HID;  // [o][h]
  const unsigned short* gb1 = w1e + (size_t)srow * DIN + c8 * 8;
  const unsigned short* gb2 = w2e + (size_t)srow * HID + c8 * 8;
  // ---- fragment row indices
  int ra0 = wm * 32 + l16, ra1 = ra0 + 16;              // A rows (tokens)
  int rh0 = wn * 64 + l16;                              // GEMM1 B rows (h)
  int ro0 = wn * 128 + l16;                             // GEMM2 B rows (o)
  f32x4 acc2[2][8];
#pragma unroll
  for (int nt = 0; nt < 8; nt++) {
    float bv = b2[e * DOUT + wn * 128 + nt * 16 + l16];
    acc2[0][nt] = (f32x4){bv, bv, bv, bv};
    acc2[1][nt] = (f32x4){bv, bv, bv, bv};
  }
  for (int hc = 0; hc < 8; hc++) {
    // ================= GEMM1: h[64x128] = x[64x512] @ W1T-chunk =============
    f32x4 acc1[2][4];
#pragma unroll
    for (int nt = 0; nt < 4; nt++) {
      float bv = b1[e * HID + hc * 128 + wn * 64 + nt * 16 + l16];
      acc1[0][nt] = (f32x4){bv, bv, bv, bv};
      acc1[1][nt] = (f32x4){bv, bv, bv, bv};
    }
    for (int ks = 0; ks < 8; ks++) {
      __syncthreads();                         // prev readers of xa/b1s done
      gld16(xa + (size_t)tid * 8, gx0 + ks * 64);
      gld16(xa + ((size_t)tid + 256) * 8, gx1 + ks * 64);
#pragma unroll
      for (int s = 0; s < 4; s++)
        gld16(b1s + ((size_t)s * 256 + tid) * 8,
              gb1 + (size_t)hc * 128 * DIN + (size_t)s * 32 * DIN + ks * 64);
      __syncthreads();                         // DMA drained (vmcnt0 @ barrier)
#pragma unroll
      for (int ki2 = 0; ki2 < 2; ki2++) {
        int cq = ki2 * 4 + quad;
        short8 af[2], bf[4];
        af[0] = *(const short8*)(xa + (ra0 * 8 + (cq ^ (ra0 & 7))) * 8);
        af[1] = *(const short8*)(xa + (ra1 * 8 + (cq ^ (ra1 & 7))) * 8);
#pragma unroll
        for (int nt = 0; nt < 4; nt++) {
          int r = rh0 + nt * 16;
          bf[nt] = *(const short8*)(b1s + (r * 8 + (cq ^ (r & 7))) * 8);
        }
#pragma unroll
        for (int mt = 0; mt < 2; mt++)
#pragma unroll
          for (int nt = 0; nt < 4; nt++)
            acc1[mt][nt] = __builtin_amdgcn_mfma_f32_16x16x32_bf16(
                af[mt], bf[nt], acc1[mt][nt], 0, 0, 0);
      }
    }
    // relu + bf16 -> swizzled h LDS (row = token, 16 chunks of 8)
#pragma unroll
    for (int mt = 0; mt < 2; mt++) {
#pragma unroll
      for (int nt = 0; nt < 4; nt++) {
        int col = wn * 64 + nt * 16 + l16;
        int c16 = col >> 3, co = col & 7;
#pragma unroll
        for (int r4 = 0; r4 < 4; r4++) {
          int r = wm * 32 + mt * 16 + quad * 4 + r4;
          float v = acc1[mt][nt][r4];
          hs[(r * 16 + (c16 ^ (r & 15))) * 8 + co] = f2bf(v > 0.f ? v : 0.f);
        }
      }
    }
    // ================= GEMM2: out[64x256] += h @ W2T-chunk ==================
    for (int k2 = 0; k2 < 2; k2++) {
      __syncthreads();                         // h written by all; prev b2s read
#pragma unroll
      for (int s = 0; s < 8; s++)
        gld16(b2s + ((size_t)s * 256 + tid) * 8,
              gb2 + (size_t)s * 32 * HID + hc * 128 + k2 * 64);
      __syncthreads();
#pragma unroll
      for (int ki2 = 0; ki2 < 2; ki2++) {
        int cq = ki2 * 4 + quad;
        int c16 = k2 * 8 + cq;
        short8 af[2], bf[8];
        af[0] = *(const short8*)(hs + (ra0 * 16 + (c16 ^ (ra0 & 15))) * 8);
        af[1] = *(const short8*)(hs + (ra1 * 16 + (c16 ^ (ra1 & 15))) * 8);
#pragma unroll
        for (int nt = 0; nt < 8; nt++) {
          int r = ro0 + nt * 16;
          bf[nt] = *(const short8*)(b2s + (r * 8 + (cq ^ (r & 7))) * 8);
        }
#pragma unroll
        for (int mt = 0; mt < 2; mt++)
#pragma unroll
          for (int nt = 0; nt < 8; nt++)
            acc2[mt][nt] = __builtin_amdgcn_mfma_f32_16x16x32_bf16(
                af[mt], bf[nt], acc2[mt][nt], 0, 0, 0);
      }
    }
  }
  // ---- epilogue: gate-weighted atomic accumulate ----
#pragma unroll
  for (int mt = 0; mt < 2; mt++) {
#pragma unroll
    for (int r4 = 0; r4 < 4; r4++) {
      int m = wm * 32 + mt * 16 + quad * 4 + r4;
      float wv = swgt[m];
      if (wv != 0.f) {
        int t = stok[m];
        float* op = out + (size_t)t * DOUT + wn * 128 + l16;
#pragma unroll
        for (int nt = 0; nt < 8; nt++)
          atomicAdd(op + nt * 16, acc2[mt][nt][r4] * wv);
      }
    }
  }
}

extern "C" void kernel_launch(void* const* d_in, const int* in_sizes, int n_in,
                              void* d_out, int out_size, void* d_ws, size_t ws_size,
                              hipStream_t stream) {
  (void)in_sizes; (void)n_in; (void)ws_size;
  const float* x     = (const float*)d_in[0];
  const float* spike = (const float*)d_in[1];
  const float* Wr    = (const float*)d_in[2];
  const float* br    = (const float*)d_in[3];
  const float* W1    = (const float*)d_in[4];
  const float* b1    = (const float*)d_in[5];
  const float* W2    = (const float*)d_in[6];
  const float* b2    = (const float*)d_in[7];
  float* out = (float*)d_out;
  char* ws = (char*)d_ws;
  unsigned short* xb  = (unsigned short*)(ws + 0);          // 33,554,432
  unsigned short* w1t = (unsigned short*)(ws + 33554432);   // 10,485,760
  unsigned short* w2t = (unsigned short*)(ws + 44040192);   //  5,242,880
  float* wrt          = (float*)(ws + 49283072);            //     20,480
  int*   cnt          = (int*)(ws + 49303552);              //         64
  int*   tok          = (int*)(ws + 49303616);              //  1,310,720
  float* wgt          = (float*)(ws + 50614336);            //  1,310,720

  hipMemsetAsync(cnt, 0, 64, stream);
  hipMemsetAsync(out, 0, (size_t)out_size * sizeof(float), stream);
  k_transpose_wr<<<1, 256, 0, stream>>>(Wr, wrt);
  k_transpose_conv<<<dim3(16, 8, 10), 256, 0, stream>>>(W1, w1t, DIN, HID);
  k_transpose_conv<<<dim3(4, 16, 10), 256, 0, stream>>>(W2, w2t, HID, DOUT);
  k_router<<<512, 256, 0, stream>>>(x, spike, wrt, br, xb, cnt, tok, wgt);
  k_moe<<<dim3(512, NEXP), 256, 0, stream>>>(xb, w1t, w2t, b1, b2, cnt, tok, wgt, out);
}